// Round 8
// baseline (161.055 us; speedup 1.0000x reference)
//
#include <hip/hip_runtime.h>
#include <hip/hip_bf16.h>
#include <stdint.h>

// DCNv2 forward, fixed shapes: N=8, Cin=Cout=256, H=W=Ho=Wo=64, K=3x3, DG=1,
// stride=1, pad=1, dil=1.
//
// R10: M64xN32 wave remap inside the EXACT R8 geometry (512 thr, grid 512,
// same colF/swizzle/prologue/sampleTap). Wave w owns co-group (w&3)*64
// (4 m-tiles) x pos-half (w>>2)*32 (2 n-tiles), acc[4][2] = 32 regs.
// B-fragment redundancy 8x -> 4x: LDS pipe (the largest serial term, 6.9k
// cyc/CU-tap of 16.8k) drops to ~4.2k. afrag w3 bytes double but the two
// pos-half waves are barrier-synced reading the same 16KB ks-slice -> L1;
// R9 showed FETCH is insensitive to afrag redundancy (caches absorb it).
// Ledger (what NOT to retry): R4/R7 reg-staging across MFMA -> spills at the
// unified 128-reg cap; R6 producer/consumer waves -> static regalloc spills;
// R5 same-wave dbuf -> no overlap; R9 small-block barrier domains -> blocks
// phase-lock regardless (symmetric contention = no slip force).

#define XH 64
#define XW 64
#define CIN 256
#define COUT 256
#define NK 9

typedef __attribute__((ext_vector_type(8))) short short8;   // 8 bf16 (4 VGPRs)
typedef __attribute__((ext_vector_type(4))) float floatx4;
typedef __attribute__((ext_vector_type(2))) float floatx2;
typedef __attribute__((ext_vector_type(4))) int   intx4;

__device__ __forceinline__ short f32_to_bf16_rne(float f) {
    union { float f; uint32_t u; } v; v.f = f;
    uint32_t u = v.u;
    uint32_t r = (u + 0x7FFFu + ((u >> 16) & 1u)) >> 16;
    return (short)(uint16_t)r;
}
__device__ __forceinline__ float bf16_to_f32(short s) {
    union { uint32_t u; float f; } v;
    v.u = ((uint32_t)(uint16_t)s) << 16;
    return v.f;
}
__device__ __forceinline__ floatx2 bf16x2_to_f32x2(uint32_t u) {
    union { uint32_t u; float f; } lo, hi;
    lo.u = u << 16;
    hi.u = u & 0xFFFF0000u;
    floatx2 r; r.x = lo.f; r.y = hi.f;
    return r;
}

union U8 { short8 s; uint32_t u[4]; };

// ---------------------------------------------------------------------------
// Combined prep (unchanged from R3/R8).
// Blocks [0,512): x (N,C,H,W) f32 -> xT (N,H,W,C) bf16, XCD-swizzled so the
//   XCD that writes rows [8x,8x+8) is the one that reads them in dcn_fused10.
// Blocks [512,800): weight swizzle -> w3 (bf16), 8 elems/thread.
__global__ void dcn_prep(const float* __restrict__ x, const float* __restrict__ w,
                         short* __restrict__ xT, short* __restrict__ w3) {
    int b = blockIdx.x;
    int tid = threadIdx.x;
    if (b < 512) {
        int xcd = b & 7, slot = b >> 3;
        int h = xcd * 8 + (slot & 7);
        int n = slot >> 3;
        int q = tid & 15;        // w-quad
        int cgh = tid >> 4;      // 0..15
        short8* ob = (short8*)(xT + ((size_t)(n * XH + h)) * (XW * CIN));
        for (int it = 0; it < 2; ++it) {
            int cg = cgh + it * 16;          // channel granule 0..31
            const float* xb = x + ((size_t)(n * CIN + cg * 8)) * (XH * XW)
                                + h * XW + q * 4;
            floatx4 r[8];
#pragma unroll
            for (int j = 0; j < 8; ++j)
                r[j] = *(const floatx4*)(xb + (size_t)j * (XH * XW));
#pragma unroll
            for (int jw = 0; jw < 4; ++jw) {
                short8 pk;
#pragma unroll
                for (int j = 0; j < 8; ++j) pk[j] = f32_to_bf16_rne(r[j][jw]);
                ob[(q * 4 + jw) * 32 + cg] = pk;
            }
        }
    } else {
        int gidx = (b - 512) * 256 + tid;    // granule index, < 73728
        int lane = gidx & 63;
        int mt   = (gidx >> 6) & 15;
        int t    = gidx >> 10;               // k*8 + ks
        int ks   = t & 7;
        int k    = t >> 3;
        int co = mt * 16 + (lane & 15);
        int c0 = ks * 32 + (lane >> 4) * 8;
        short8 pk;
#pragma unroll
        for (int j = 0; j < 8; ++j)
            pk[j] = f32_to_bf16_rne(w[(co * CIN + c0 + j) * NK + k]);
        *(short8*)&w3[(size_t)gidx * 8] = pk;
    }
}

// ---------------------------------------------------------------------------
// Fused kernel. grid = N*Ho = 512, 512 threads (8 waves), XCD-swizzled.
// Per tap: phase A (paired gathers -> colF) | barrier | phase B (8 MFMA
// K-steps; wave w owns co-group (w&3)*64 x pos-half (w>>2)*32) | barrier.
__launch_bounds__(512, 4)
__global__ void dcn_fused10(const short* __restrict__ xT,
                            const float* __restrict__ off,
                            const float* __restrict__ msk,
                            const short* __restrict__ w3,
                            const float* __restrict__ bias,
                            float* __restrict__ out) {
    // colF: 2048 granules of 16B. granule(chg,pos) at g = chg*64+(pos^(chg&7))
    __shared__ short   colF[2048 * 8];       // 32768 B
    __shared__ floatx4 pairW[576];           //  9216 B
    __shared__ ushort4 pairO[576];           //  4608 B (raw spatial offs)

    const int bid = blockIdx.x;
    const int xcd = bid & 7, slot = bid >> 3;
    const int ho = xcd * 8 + (slot & 7);     // XCD x owns ho band [8x, 8x+8)
    const int n  = slot >> 3;
    const int tid  = threadIdx.x;
    const int wave = tid >> 6;
    const int lane = tid & 63;
    const int quad = lane >> 4, cl = lane & 15;
    const int mg = wave & 3;                 // co-group (4 m-tiles of 16)
    const int ph = wave >> 2;                // pos-half (2 n-tiles of 16)

    // ---- bilinear params for 576 (wo, tap) pairs (mask folded into weights).
    for (int p = tid; p < 576; p += 512) {
        int wo = p & 63, k = p >> 6;
        int obase = ((n * 18 + 2 * k) * XH + ho) * XW + wo;
        float dy = off[obase];
        float dx = off[obase + XH * XW];
        float mm = msk[((n * NK + k) * XH + ho) * XW + wo];
        float y  = (float)(ho - 1 + k / 3) + dy;
        float xs = (float)(wo - 1 + k % 3) + dx;
        float y0f = floorf(y), x0f = floorf(xs);
        float fy = y - y0f, fx = xs - x0f;
        int y0 = (int)y0f, x0 = (int)x0f;
        float vy0 = (y0 >= 0  && y0 < XH)     ? 1.f : 0.f;
        float vy1 = (y0 >= -1 && y0 < XH - 1) ? 1.f : 0.f;
        float vx0 = (x0 >= 0  && x0 < XW)     ? 1.f : 0.f;
        float vx1 = (x0 >= -1 && x0 < XW - 1) ? 1.f : 0.f;
        floatx4 wv;
        wv.x = (1.f - fy) * (1.f - fx) * mm * vy0 * vx0;
        wv.y = (1.f - fy) * fx         * mm * vy0 * vx1;
        wv.z = fy         * (1.f - fx) * mm * vy1 * vx0;
        wv.w = fy         * fx         * mm * vy1 * vx1;
        int y0c = min(max(y0, 0), XH - 1), y1c = min(max(y0 + 1, 0), XH - 1);
        int x0c = min(max(x0, 0), XW - 1), x1c = min(max(x0 + 1, 0), XW - 1);
        ushort4 ov;
        ov.x = (unsigned short)(y0c * XW + x0c);
        ov.y = (unsigned short)(y0c * XW + x1c);
        ov.z = (unsigned short)(y1c * XW + x0c);
        ov.w = (unsigned short)(y1c * XW + x1c);
        pairW[p] = wv;
        pairO[p] = ov;
    }
    __syncthreads();

    floatx4 acc[4][2];
#pragma unroll
    for (int mt = 0; mt < 4; ++mt)
#pragma unroll
        for (int nt = 0; nt < 2; ++nt)
            acc[mt][nt] = (floatx4)(0.f);

    const short8* xTv = (const short8*)(xT + (size_t)n * (XH * XW * CIN));
    const short8* w3v = (const short8*)w3;

    // ---- phase-B address hoists: swizzle has only 2 per-ks variants.
    // pos-block index pb = ph*2 + nt (this wave reads pos [ph*32, ph*32+32)).
    int boffE[2], boffO[2];
#pragma unroll
    for (int nt = 0; nt < 2; ++nt) {
        int base = (ph * 2 + nt) * 16 + cl;
        boffE[nt] = base ^ quad;               // ks even: sw = quad
        boffO[nt] = (base ^ quad) ^ 4;         // ks odd:  sw = quad^4
    }
    const short8* cbase = (const short8*)colF;

    // ---- phase A: paired gathers (chg, chg+16). 1024 pairs, 2 per thread.
    // 16 lanes x 16B = 256B contiguous per (pos, corner); 2nd granule at
    // +256B folds into the load offset. Full 0..7 XOR coverage on ds_writes
    // -> 0 bank conflicts (R8-verified).
    auto sampleTap = [&](int k) {
        for (int it = 0; it < 2; ++it) {
            int pidx = it * 512 + tid;
            int cp  = pidx & 15;
            int pos = pidx >> 4;
            int p = k * 64 + pos;
            ushort4 ov = pairO[p];
            const short8* q00 = xTv + ((int)ov.x * 32 + cp);
            const short8* q01 = xTv + ((int)ov.y * 32 + cp);
            const short8* q10 = xTv + ((int)ov.z * 32 + cp);
            const short8* q11 = xTv + ((int)ov.w * 32 + cp);
            U8 a0, b0, c0, d0, a1, b1, c1, d1;
            a0.s = q00[0]; a1.s = q00[16];
            b0.s = q01[0]; b1.s = q01[16];
            c0.s = q10[0]; c1.s = q10[16];
            d0.s = q11[0]; d1.s = q11[16];
            floatx4 wv = pairW[p];
            U8 pk0, pk1;
#pragma unroll
            for (int i = 0; i < 4; ++i) {
                floatx2 v0 = bf16x2_to_f32x2(a0.u[i]) * wv.x
                           + bf16x2_to_f32x2(b0.u[i]) * wv.y
                           + bf16x2_to_f32x2(c0.u[i]) * wv.z
                           + bf16x2_to_f32x2(d0.u[i]) * wv.w;
                floatx2 v1 = bf16x2_to_f32x2(a1.u[i]) * wv.x
                           + bf16x2_to_f32x2(b1.u[i]) * wv.y
                           + bf16x2_to_f32x2(c1.u[i]) * wv.z
                           + bf16x2_to_f32x2(d1.u[i]) * wv.w;
                float2 f0; f0.x = v0.x; f0.y = v0.y;
                float2 f1; f1.x = v1.x; f1.y = v1.y;
                __hip_bfloat162 h0 = __float22bfloat162_rn(f0);
                __hip_bfloat162 h1 = __float22bfloat162_rn(f1);
                __builtin_memcpy(&pk0.u[i], &h0, 4);
                __builtin_memcpy(&pk1.u[i], &h1, 4);
            }
            int sw = pos ^ (cp & 7);
            *(short8*)&colF[(cp * 64 + sw) * 8] = pk0.s;
            *(short8*)&colF[((cp + 16) * 64 + sw) * 8] = pk1.s;
        }
    };

    // ---- prologue: tap 0 ----
    sampleTap(0);

#pragma unroll 1
    for (int k = 0; k < NK; ++k) {
        __syncthreads();                       // phase A of tap k complete

        // ---- phase B: 8 K-steps; 4 m-tiles (co-group mg) x 2 n-tiles ----
        __builtin_amdgcn_s_setprio(1);
        const short8* ap = w3v + ((k * 8 * 16) + mg * 4) * 64 + lane;
#pragma unroll
        for (int ks = 0; ks < 8; ++ks) {
            short8 afrag[4];
#pragma unroll
            for (int mt = 0; mt < 4; ++mt)
                afrag[mt] = ap[mt * 64];
            const short8* cb = cbase + (ks * 256 + quad * 64);
            short8 bfrag[2];
#pragma unroll
            for (int nt = 0; nt < 2; ++nt)
                bfrag[nt] = cb[(ks & 1) ? boffO[nt] : boffE[nt]];
#pragma unroll
            for (int mt = 0; mt < 4; ++mt)
#pragma unroll
                for (int nt = 0; nt < 2; ++nt)
                    acc[mt][nt] = __builtin_amdgcn_mfma_f32_16x16x32_bf16(
                        afrag[mt], bfrag[nt], acc[mt][nt], 0, 0, 0);
            ap += 16 * 64;
        }
        __builtin_amdgcn_s_setprio(0);

        if (k < NK - 1) {
            __syncthreads();                   // phase B done reading colF
            sampleTap(k + 1);
        }
    }

    // ---- epilogue: D layout col=lane&15 (pos), row=(lane>>4)*4+reg (co) ----
#pragma unroll
    for (int mt = 0; mt < 4; ++mt) {
        int cobase = (mg * 4 + mt) * 16 + quad * 4;
#pragma unroll
        for (int r = 0; r < 4; ++r) {
            int co = cobase + r;
            float b = bias[co];
            float* op = out + (((size_t)n * COUT + co) * XH + ho) * XW + ph * 32;
#pragma unroll
            for (int nt = 0; nt < 2; ++nt)
                op[nt * 16 + cl] = acc[mt][nt][r] + b;
        }
    }
}

// ===========================================================================
// Fallback 1 (ws in [1.18MB, 18MB)): round-1 fused kernel (NCHW gathers).
__global__ void dcn_wprep_v1(const float* __restrict__ w, short* __restrict__ w3) {
    int idx = blockIdx.x * 256 + threadIdx.x;
    if (idx >= 8 * 9 * 16 * 64 * 8) return;
    int j    = idx & 7;
    int lane = (idx >> 3) & 63;
    int mt   = (idx >> 9) & 15;
    int t    = idx >> 13;
    int ks   = t % 9;
    int cc   = t / 9;
    int co = mt * 16 + (lane & 15);
    int c  = cc * 32 + (lane >> 4) * 8 + j;
    w3[idx] = f32_to_bf16_rne(w[(co * CIN + c) * NK + ks]);
}

__launch_bounds__(256, 2)
__global__ void dcn_fused_v1(const float* __restrict__ x,
                             const float* __restrict__ off,
                             const float* __restrict__ msk,
                             const short* __restrict__ w3,
                             const float* __restrict__ bias,
                             float* __restrict__ out) {
    __shared__ short  colF[2304 * 8];
    __shared__ floatx4 pairW[576];
    __shared__ intx4   pairO[576];

    const int bid = blockIdx.x;
    const int n  = bid >> 6;
    const int ho = bid & 63;
    const int tid  = threadIdx.x;
    const int wave = tid >> 6;
    const int lane = tid & 63;

    for (int p = tid; p < 576; p += 256) {
        int wo = p & 63, k = p >> 6;
        int obase = ((n * 18 + 2 * k) * XH + ho) * XW + wo;
        float dy = off[obase];
        float dx = off[obase + XH * XW];
        float mm = msk[((n * NK + k) * XH + ho) * XW + wo];
        float y  = (float)(ho - 1 + k / 3) + dy;
        float xs = (float)(wo - 1 + k % 3) + dx;
        float y0f = floorf(y), x0f = floorf(xs);
        float fy = y - y0f, fx = xs - x0f;
        int y0 = (int)y0f, x0 = (int)x0f;
        float vy0 = (y0 >= 0  && y0 < XH)     ? 1.f : 0.f;
        float vy1 = (y0 >= -1 && y0 < XH - 1) ? 1.f : 0.f;
        float vx0 = (x0 >= 0  && x0 < XW)     ? 1.f : 0.f;
        float vx1 = (x0 >= -1 && x0 < XW - 1) ? 1.f : 0.f;
        floatx4 wv;
        wv.x = (1.f - fy) * (1.f - fx) * mm * vy0 * vx0;
        wv.y = (1.f - fy) * fx         * mm * vy0 * vx1;
        wv.z = fy         * (1.f - fx) * mm * vy1 * vx0;
        wv.w = fy         * fx         * mm * vy1 * vx1;
        int y0c = min(max(y0, 0), XH - 1), y1c = min(max(y0 + 1, 0), XH - 1);
        int x0c = min(max(x0, 0), XW - 1), x1c = min(max(x0 + 1, 0), XW - 1);
        intx4 ov;
        ov.x = y0c * XW + x0c; ov.y = y0c * XW + x1c;
        ov.z = y1c * XW + x0c; ov.w = y1c * XW + x1c;
        pairW[p] = wv;
        pairO[p] = ov;
    }
    __syncthreads();

    floatx4 acc[4][4];
#pragma unroll
    for (int mt = 0; mt < 4; ++mt)
#pragma unroll
        for (int nt = 0; nt < 4; ++nt)
            acc[mt][nt] = (floatx4)(0.f);

    const float* xn = x + (size_t)n * CIN * (XH * XW);
    const short8* w3v = (const short8*)w3;

    for (int cc = 0; cc < 8; ++cc) {
        __syncthreads();
        for (int it = 0; it < 9; ++it) {
            int item = it * 256 + tid;
            int pos  = item & 63;
            int r    = item >> 6;
            int k    = r >> 2;
            int csub = r & 3;
            int p = k * 64 + pos;
            floatx4 wv = pairW[p];
            intx4   ov = pairO[p];
            const float* xc = xn + (size_t)(cc * 32 + csub * 8) * (XH * XW);
            short8 pk;
#pragma unroll
            for (int i = 0; i < 8; ++i) {
                const float* xp = xc + i * (XH * XW);
                float v = wv.x * xp[ov.x] + wv.y * xp[ov.y] +
                          wv.z * xp[ov.z] + wv.w * xp[ov.w];
                pk[i] = f32_to_bf16_rne(v);
            }
            *(short8*)&colF[(((k * 4 + csub) * 64) + pos) * 8] = pk;
        }
        __syncthreads();

        const int quad = lane >> 4, cl = lane & 15;
        for (int ks = 0; ks < 9; ++ks) {
            short8 afrag[4];
#pragma unroll
            for (int mt = 0; mt < 4; ++mt) {
                int mtg = wave * 4 + mt;
                afrag[mt] = w3v[(((cc * 9 + ks) * 16 + mtg) * 64) + lane];
            }
            short8 bfrag[4];
#pragma unroll
            for (int nt = 0; nt < 4; ++nt)
                bfrag[nt] = *(const short8*)
                    &colF[(((ks * 4 + quad) * 64) + nt * 16 + cl) * 8];
#pragma unroll
            for (int mt = 0; mt < 4; ++mt)
#pragma unroll
                for (int nt = 0; nt < 4; ++nt)
                    acc[mt][nt] = __builtin_amdgcn_mfma_f32_16x16x32_bf16(
                        afrag[mt], bfrag[nt], acc[mt][nt], 0, 0, 0);
        }
    }

    const int quad = lane >> 4, cl = lane & 15;
#pragma unroll
    for (int mt = 0; mt < 4; ++mt) {
        int cobase = (wave * 4 + mt) * 16 + quad * 4;
#pragma unroll
        for (int r = 0; r < 4; ++r) {
            int co = cobase + r;
            float b = bias[co];
            float* op = out + (((size_t)n * COUT + co) * XH + ho) * XW;
#pragma unroll
            for (int nt = 0; nt < 4; ++nt)
                op[nt * 16 + cl] = acc[mt][nt][r] + b;
        }
    }
}

// Fallback 2: naive (ws < 1.18MB).
__global__ void dcn_naive(const float* __restrict__ x,
                          const float* __restrict__ off,
                          const float* __restrict__ msk,
                          const float* __restrict__ w,
                          const float* __restrict__ bias,
                          float* __restrict__ out) {
    int idx = blockIdx.x * 256 + threadIdx.x;
    if (idx >= 8 * COUT * XH * XW) return;
    int wo = idx & 63, ho = (idx >> 6) & 63, co = (idx >> 12) & 255, n = idx >> 20;
    float acc = bias[co];
    for (int k = 0; k < NK; ++k) {
        int obase = ((n * 18 + 2 * k) * XH + ho) * XW + wo;
        float dy = off[obase];
        float dx = off[obase + XH * XW];
        float mm = msk[((n * NK + k) * XH + ho) * XW + wo];
        float y  = (float)(ho - 1 + k / 3) + dy;
        float xs = (float)(wo - 1 + k % 3) + dx;
        float y0f = floorf(y), x0f = floorf(xs);
        float fy = y - y0f, fx = xs - x0f;
        int y0 = (int)y0f, x0 = (int)x0f;
        float vy0 = (y0 >= 0  && y0 < XH)     ? 1.f : 0.f;
        float vy1 = (y0 >= -1 && y0 < XH - 1) ? 1.f : 0.f;
        float vx0 = (x0 >= 0  && x0 < XW)     ? 1.f : 0.f;
        float vx1 = (x0 >= -1 && x0 < XW - 1) ? 1.f : 0.f;
        float w00 = (1.f - fy) * (1.f - fx) * mm * vy0 * vx0;
        float w01 = (1.f - fy) * fx         * mm * vy0 * vx1;
        float w10 = fy         * (1.f - fx) * mm * vy1 * vx0;
        float w11 = fy         * fx         * mm * vy1 * vx1;
        int y0c = min(max(y0, 0), XH - 1), y1c = min(max(y0 + 1, 0), XH - 1);
        int x0c = min(max(x0, 0), XW - 1), x1c = min(max(x0 + 1, 0), XW - 1);
        int o00 = y0c * XW + x0c, o01 = y0c * XW + x1c;
        int o10 = y1c * XW + x0c, o11 = y1c * XW + x1c;
        for (int c = 0; c < CIN; ++c) {
            const float* xp = x + ((size_t)(n * CIN + c)) * (XH * XW);
            float v = w00 * xp[o00] + w01 * xp[o01] + w10 * xp[o10] + w11 * xp[o11];
            acc += v * w[(co * CIN + c) * NK + k];
        }
    }
    out[idx] = acc;
}

// ---------------------------------------------------------------------------
extern "C" void kernel_launch(void* const* d_in, const int* in_sizes, int n_in,
                              void* d_out, int out_size, void* d_ws, size_t ws_size,
                              hipStream_t stream) {
    const float* x    = (const float*)d_in[0];
    const float* off  = (const float*)d_in[1];
    const float* msk  = (const float*)d_in[2];
    const float* w    = (const float*)d_in[3];
    const float* bias = (const float*)d_in[4];
    float* out = (float*)d_out;

    const size_t W3_BYTES = (size_t)9 * 8 * 16 * 64 * 8 * sizeof(short); // 1179648
    const size_t XT_BYTES = (size_t)8 * XH * XW * CIN * sizeof(short);   // 16777216

    if (ws_size >= W3_BYTES + XT_BYTES) {
        short* w3 = (short*)d_ws;
        short* xT = (short*)((char*)d_ws + W3_BYTES);
        dcn_prep<<<512 + 288, 256, 0, stream>>>(x, w, xT, w3);
        dcn_fused10<<<8 * 64, 512, 0, stream>>>(xT, off, msk, w3, bias, out);
    } else if (ws_size >= W3_BYTES) {
        short* w3 = (short*)d_ws;
        dcn_wprep_v1<<<(8 * 9 * 16 * 64 * 8 + 255) / 256, 256, 0, stream>>>(w, w3);
        dcn_fused_v1<<<8 * 64, 256, 0, stream>>>(x, off, msk, w3, bias, out);
    } else {
        dcn_naive<<<(8 * COUT * XH * XW + 255) / 256, 256, 0, stream>>>(
            x, off, msk, w, bias, out);
    }
}

// Round 9
// 151.185 us; speedup vs baseline: 1.0653x; 1.0653x over previous
//
#include <hip/hip_runtime.h>
#include <hip/hip_bf16.h>
#include <stdint.h>

// DCNv2 forward, fixed shapes: N=8, Cin=Cout=256, H=W=Ho=Wo=64, K=3x3, DG=1,
// stride=1, pad=1, dil=1.
//
// R11: R8 schedule (best: 63.0us) with 32x32x16 MFMA, wave <-> co-tile 1:1.
// Session ledger (mechanisms, do NOT retry):
//   R4/R7: reg-staged gathers across MFMA -> scratch spill at unified 128-reg
//          cap (WRITE_SIZE +17..43MB).
//   R5:    same-wave dbuf, 1 barrier/tap -> barrier re-aligns waves, no overlap.
//   R6:    producer/consumer waves -> regalloc static, producers carry dead
//          acc AGPRs -> spill; 4-way write conflicts from adjacent-chg pairs.
//   R9:    4 small barrier domains/CU -> blocks phase-lock anyway (symmetric
//          contention, no slip force). Prologue doubling cost extra.
//   R10:   A-red 2 x B-red 4 remap -> afrag L2 traffic +590MB = +17us.
//          QUANTIFIED: A-redundancy ~17us/unit (L2), B-redundancy ~1.4us/unit
//          (LDS). R8's A-red=1 x B-red=8 is the optimal corner.
// R11 change: 16x16x32 -> 32x32x16. A-red stays 1, B/LDS identical; MFMA
// cycles -17% (4.85*1024 -> 8.07*512 per CU-tap) and MFMA issue slots halve.

#define XH 64
#define XW 64
#define CIN 256
#define COUT 256
#define NK 9

typedef __attribute__((ext_vector_type(8)))  short short8;   // 8 bf16 (4 VGPRs)
typedef __attribute__((ext_vector_type(4)))  float floatx4;
typedef __attribute__((ext_vector_type(16))) float floatx16;
typedef __attribute__((ext_vector_type(2)))  float floatx2;
typedef __attribute__((ext_vector_type(4)))  int   intx4;

__device__ __forceinline__ short f32_to_bf16_rne(float f) {
    union { float f; uint32_t u; } v; v.f = f;
    uint32_t u = v.u;
    uint32_t r = (u + 0x7FFFu + ((u >> 16) & 1u)) >> 16;
    return (short)(uint16_t)r;
}
__device__ __forceinline__ floatx2 bf16x2_to_f32x2(uint32_t u) {
    union { uint32_t u; float f; } lo, hi;
    lo.u = u << 16;
    hi.u = u & 0xFFFF0000u;
    floatx2 r; r.x = lo.f; r.y = hi.f;
    return r;
}

union U8 { short8 s; uint32_t u[4]; };

// ---------------------------------------------------------------------------
// Combined prep.
// Blocks [0,512): x (N,C,H,W) f32 -> xT (N,H,W,C) bf16, XCD-swizzled
//   (unchanged from R8).
// Blocks [512,800): weight swizzle -> w3 (bf16) in 32x32x16 A-frag layout:
//   w3[((k*16+ks16)*8 + cotile)*64 + lane] granule (8 bf16) =
//     W[cotile*32+(lane&31)][ks16*16+(lane>>5)*8 + j][k], j=0..7
__global__ void dcn_prep(const float* __restrict__ x, const float* __restrict__ w,
                         short* __restrict__ xT, short* __restrict__ w3) {
    int b = blockIdx.x;
    int tid = threadIdx.x;
    if (b < 512) {
        int xcd = b & 7, slot = b >> 3;
        int h = xcd * 8 + (slot & 7);
        int n = slot >> 3;
        int q = tid & 15;        // w-quad
        int cgh = tid >> 4;      // 0..15
        short8* ob = (short8*)(xT + ((size_t)(n * XH + h)) * (XW * CIN));
        for (int it = 0; it < 2; ++it) {
            int cg = cgh + it * 16;          // channel granule 0..31
            const float* xb = x + ((size_t)(n * CIN + cg * 8)) * (XH * XW)
                                + h * XW + q * 4;
            floatx4 r[8];
#pragma unroll
            for (int j = 0; j < 8; ++j)
                r[j] = *(const floatx4*)(xb + (size_t)j * (XH * XW));
#pragma unroll
            for (int jw = 0; jw < 4; ++jw) {
                short8 pk;
#pragma unroll
                for (int j = 0; j < 8; ++j) pk[j] = f32_to_bf16_rne(r[j][jw]);
                ob[(q * 4 + jw) * 32 + cg] = pk;
            }
        }
    } else {
        int gidx = (b - 512) * 256 + tid;    // granule index, < 73728
        int lane = gidx & 63;
        int cotile = (gidx >> 6) & 7;
        int t    = gidx >> 9;                // k*16 + ks16
        int ks16 = t & 15;
        int k    = t >> 4;
        int co = cotile * 32 + (lane & 31);
        int c0 = ks16 * 16 + (lane >> 5) * 8;
        short8 pk;
#pragma unroll
        for (int j = 0; j < 8; ++j)
            pk[j] = f32_to_bf16_rne(w[(co * CIN + c0 + j) * NK + k]);
        *(short8*)&w3[(size_t)gidx * 8] = pk;
    }
}

// ---------------------------------------------------------------------------
// Fused kernel. grid = N*Ho = 512, 512 threads (8 waves), XCD-swizzled.
// Per tap: phase A (paired gathers -> colF) | barrier | phase B (16 K-steps
// of 16 ch, 32x32x16 MFMA; wave = co-tile, both pos-tiles) | barrier.
__launch_bounds__(512, 4)
__global__ void dcn_fused11(const short* __restrict__ xT,
                            const float* __restrict__ off,
                            const float* __restrict__ msk,
                            const short* __restrict__ w3,
                            const float* __restrict__ bias,
                            float* __restrict__ out) {
    // colF: 2048 granules of 16B. granule(chg,pos) at g = chg*64+(pos^(chg&7))
    __shared__ short   colF[2048 * 8];       // 32768 B
    __shared__ floatx4 pairW[576];           //  9216 B
    __shared__ ushort4 pairO[576];           //  4608 B (raw spatial offs)

    const int bid = blockIdx.x;
    const int xcd = bid & 7, slot = bid >> 3;
    const int ho = xcd * 8 + (slot & 7);     // XCD x owns ho band [8x, 8x+8)
    const int n  = slot >> 3;
    const int tid  = threadIdx.x;
    const int wave = tid >> 6;               // = co-tile 0..7
    const int lane = tid & 63;
    const int pos_l = lane & 31, hk = lane >> 5;

    // ---- bilinear params for 576 (wo, tap) pairs (mask folded into weights).
    for (int p = tid; p < 576; p += 512) {
        int wo = p & 63, k = p >> 6;
        int obase = ((n * 18 + 2 * k) * XH + ho) * XW + wo;
        float dy = off[obase];
        float dx = off[obase + XH * XW];
        float mm = msk[((n * NK + k) * XH + ho) * XW + wo];
        float y  = (float)(ho - 1 + k / 3) + dy;
        float xs = (float)(wo - 1 + k % 3) + dx;
        float y0f = floorf(y), x0f = floorf(xs);
        float fy = y - y0f, fx = xs - x0f;
        int y0 = (int)y0f, x0 = (int)x0f;
        float vy0 = (y0 >= 0  && y0 < XH)     ? 1.f : 0.f;
        float vy1 = (y0 >= -1 && y0 < XH - 1) ? 1.f : 0.f;
        float vx0 = (x0 >= 0  && x0 < XW)     ? 1.f : 0.f;
        float vx1 = (x0 >= -1 && x0 < XW - 1) ? 1.f : 0.f;
        floatx4 wv;
        wv.x = (1.f - fy) * (1.f - fx) * mm * vy0 * vx0;
        wv.y = (1.f - fy) * fx         * mm * vy0 * vx1;
        wv.z = fy         * (1.f - fx) * mm * vy1 * vx0;
        wv.w = fy         * fx         * mm * vy1 * vx1;
        int y0c = min(max(y0, 0), XH - 1), y1c = min(max(y0 + 1, 0), XH - 1);
        int x0c = min(max(x0, 0), XW - 1), x1c = min(max(x0 + 1, 0), XW - 1);
        ushort4 ov;
        ov.x = (unsigned short)(y0c * XW + x0c);
        ov.y = (unsigned short)(y0c * XW + x1c);
        ov.z = (unsigned short)(y1c * XW + x0c);
        ov.w = (unsigned short)(y1c * XW + x1c);
        pairW[p] = wv;
        pairO[p] = ov;
    }
    __syncthreads();

    floatx16 acc0 = (floatx16)(0.f);         // pos-tile 0
    floatx16 acc1 = (floatx16)(0.f);         // pos-tile 1

    const short8* xTv = (const short8*)(xT + (size_t)n * (XH * XW * CIN));
    const short8* w3v = (const short8*)w3;

    // ---- phase-B address hoists: chg = 2*ks16 + hk; sw = chg&7 has period 4
    // in ks16 -> precompute boff[m][pt] for m = ks16&3 (static-indexed in the
    // fully-unrolled kstep loop; rule-#20 safe).
    int boff[4][2];
#pragma unroll
    for (int m = 0; m < 4; ++m) {
        int sw = 2 * m + hk;
#pragma unroll
        for (int pt = 0; pt < 2; ++pt)
            boff[m][pt] = (pt * 32 + pos_l) ^ sw;
    }
    const short8* cbase = (const short8*)colF;

    // ---- phase A: paired gathers (chg, chg+16). 1024 pairs, 2 per thread.
    // Identical to R8 (verified 0 conflicts, 256B+256B runs per corner).
    auto sampleTap = [&](int k) {
        for (int it = 0; it < 2; ++it) {
            int pidx = it * 512 + tid;
            int cp  = pidx & 15;
            int pos = pidx >> 4;
            int p = k * 64 + pos;
            ushort4 ov = pairO[p];
            const short8* q00 = xTv + ((int)ov.x * 32 + cp);
            const short8* q01 = xTv + ((int)ov.y * 32 + cp);
            const short8* q10 = xTv + ((int)ov.z * 32 + cp);
            const short8* q11 = xTv + ((int)ov.w * 32 + cp);
            U8 a0, b0, c0, d0, a1, b1, c1, d1;
            a0.s = q00[0]; a1.s = q00[16];
            b0.s = q01[0]; b1.s = q01[16];
            c0.s = q10[0]; c1.s = q10[16];
            d0.s = q11[0]; d1.s = q11[16];
            floatx4 wv = pairW[p];
            U8 pk0, pk1;
#pragma unroll
            for (int i = 0; i < 4; ++i) {
                floatx2 v0 = bf16x2_to_f32x2(a0.u[i]) * wv.x
                           + bf16x2_to_f32x2(b0.u[i]) * wv.y
                           + bf16x2_to_f32x2(c0.u[i]) * wv.z
                           + bf16x2_to_f32x2(d0.u[i]) * wv.w;
                floatx2 v1 = bf16x2_to_f32x2(a1.u[i]) * wv.x
                           + bf16x2_to_f32x2(b1.u[i]) * wv.y
                           + bf16x2_to_f32x2(c1.u[i]) * wv.z
                           + bf16x2_to_f32x2(d1.u[i]) * wv.w;
                float2 f0; f0.x = v0.x; f0.y = v0.y;
                float2 f1; f1.x = v1.x; f1.y = v1.y;
                __hip_bfloat162 h0 = __float22bfloat162_rn(f0);
                __hip_bfloat162 h1 = __float22bfloat162_rn(f1);
                __builtin_memcpy(&pk0.u[i], &h0, 4);
                __builtin_memcpy(&pk1.u[i], &h1, 4);
            }
            int sw = pos ^ (cp & 7);
            *(short8*)&colF[(cp * 64 + sw) * 8] = pk0.s;
            *(short8*)&colF[((cp + 16) * 64 + sw) * 8] = pk1.s;
        }
    };

    // ---- prologue: tap 0 ----
    sampleTap(0);

#pragma unroll 1
    for (int k = 0; k < NK; ++k) {
        __syncthreads();                       // phase A of tap k complete

        // ---- phase B: 16 K-steps of 16 channels, 2 MFMA each ----
        __builtin_amdgcn_s_setprio(1);
        const short8* ap = w3v + ((size_t)(k * 16) * 8 + wave) * 64 + lane;
#pragma unroll
        for (int ks16 = 0; ks16 < 16; ++ks16) {
            short8 afrag = ap[(size_t)ks16 * 8 * 64];
            // B granule: chg = 2*ks16 + hk, pos = pt*32 + pos_l
            const short8* cb = cbase + (2 * ks16 + hk) * 64;
            short8 b0 = cb[boff[ks16 & 3][0]];
            short8 b1 = cb[boff[ks16 & 3][1]];
            acc0 = __builtin_amdgcn_mfma_f32_32x32x16_bf16(afrag, b0, acc0, 0, 0, 0);
            acc1 = __builtin_amdgcn_mfma_f32_32x32x16_bf16(afrag, b1, acc1, 0, 0, 0);
        }
        __builtin_amdgcn_s_setprio(0);

        if (k < NK - 1) {
            __syncthreads();                   // phase B done reading colF
            sampleTap(k + 1);
        }
    }

    // ---- epilogue: 32x32 C/D layout: col(pos) = lane&31,
    // row = (r&3) + 8*(r>>2) + 4*(lane>>5), r in [0,16) ----
#pragma unroll
    for (int r = 0; r < 16; ++r) {
        int row = (r & 3) + 8 * (r >> 2) + 4 * hk;
        int co = wave * 32 + row;
        float b = bias[co];
        float* op = out + (((size_t)n * COUT + co) * XH + ho) * XW + pos_l;
        op[0]  = acc0[r] + b;
        op[32] = acc1[r] + b;
    }
}

// ===========================================================================
// Fallback 1 (ws in [1.18MB, 18MB)): round-1 fused kernel (NCHW gathers).
__global__ void dcn_wprep_v1(const float* __restrict__ w, short* __restrict__ w3) {
    int idx = blockIdx.x * 256 + threadIdx.x;
    if (idx >= 8 * 9 * 16 * 64 * 8) return;
    int j    = idx & 7;
    int lane = (idx >> 3) & 63;
    int mt   = (idx >> 9) & 15;
    int t    = idx >> 13;
    int ks   = t % 9;
    int cc   = t / 9;
    int co = mt * 16 + (lane & 15);
    int c  = cc * 32 + (lane >> 4) * 8 + j;
    w3[idx] = f32_to_bf16_rne(w[(co * CIN + c) * NK + ks]);
}

__launch_bounds__(256, 2)
__global__ void dcn_fused_v1(const float* __restrict__ x,
                             const float* __restrict__ off,
                             const float* __restrict__ msk,
                             const short* __restrict__ w3,
                             const float* __restrict__ bias,
                             float* __restrict__ out) {
    __shared__ short  colF[2304 * 8];
    __shared__ floatx4 pairW[576];
    __shared__ intx4   pairO[576];

    const int bid = blockIdx.x;
    const int n  = bid >> 6;
    const int ho = bid & 63;
    const int tid  = threadIdx.x;
    const int wave = tid >> 6;
    const int lane = tid & 63;

    for (int p = tid; p < 576; p += 256) {
        int wo = p & 63, k = p >> 6;
        int obase = ((n * 18 + 2 * k) * XH + ho) * XW + wo;
        float dy = off[obase];
        float dx = off[obase + XH * XW];
        float mm = msk[((n * NK + k) * XH + ho) * XW + wo];
        float y  = (float)(ho - 1 + k / 3) + dy;
        float xs = (float)(wo - 1 + k % 3) + dx;
        float y0f = floorf(y), x0f = floorf(xs);
        float fy = y - y0f, fx = xs - x0f;
        int y0 = (int)y0f, x0 = (int)x0f;
        float vy0 = (y0 >= 0  && y0 < XH)     ? 1.f : 0.f;
        float vy1 = (y0 >= -1 && y0 < XH - 1) ? 1.f : 0.f;
        float vx0 = (x0 >= 0  && x0 < XW)     ? 1.f : 0.f;
        float vx1 = (x0 >= -1 && x0 < XW - 1) ? 1.f : 0.f;
        floatx4 wv;
        wv.x = (1.f - fy) * (1.f - fx) * mm * vy0 * vx0;
        wv.y = (1.f - fy) * fx         * mm * vy0 * vx1;
        wv.z = fy         * (1.f - fx) * mm * vy1 * vx0;
        wv.w = fy         * fx         * mm * vy1 * vx1;
        int y0c = min(max(y0, 0), XH - 1), y1c = min(max(y0 + 1, 0), XH - 1);
        int x0c = min(max(x0, 0), XW - 1), x1c = min(max(x0 + 1, 0), XW - 1);
        intx4 ov;
        ov.x = y0c * XW + x0c; ov.y = y0c * XW + x1c;
        ov.z = y1c * XW + x0c; ov.w = y1c * XW + x1c;
        pairW[p] = wv;
        pairO[p] = ov;
    }
    __syncthreads();

    floatx4 acc[4][4];
#pragma unroll
    for (int mt = 0; mt < 4; ++mt)
#pragma unroll
        for (int nt = 0; nt < 4; ++nt)
            acc[mt][nt] = (floatx4)(0.f);

    const float* xn = x + (size_t)n * CIN * (XH * XW);
    const short8* w3v = (const short8*)w3;

    for (int cc = 0; cc < 8; ++cc) {
        __syncthreads();
        for (int it = 0; it < 9; ++it) {
            int item = it * 256 + tid;
            int pos  = item & 63;
            int r    = item >> 6;
            int k    = r >> 2;
            int csub = r & 3;
            int p = k * 64 + pos;
            floatx4 wv = pairW[p];
            intx4   ov = pairO[p];
            const float* xc = xn + (size_t)(cc * 32 + csub * 8) * (XH * XW);
            short8 pk;
#pragma unroll
            for (int i = 0; i < 8; ++i) {
                const float* xp = xc + i * (XH * XW);
                float v = wv.x * xp[ov.x] + wv.y * xp[ov.y] +
                          wv.z * xp[ov.z] + wv.w * xp[ov.w];
                pk[i] = f32_to_bf16_rne(v);
            }
            *(short8*)&colF[(((k * 4 + csub) * 64) + pos) * 8] = pk;
        }
        __syncthreads();

        const int quad = lane >> 4, cl = lane & 15;
        for (int ks = 0; ks < 9; ++ks) {
            short8 afrag[4];
#pragma unroll
            for (int mt = 0; mt < 4; ++mt) {
                int mtg = wave * 4 + mt;
                afrag[mt] = w3v[(((cc * 9 + ks) * 16 + mtg) * 64) + lane];
            }
            short8 bfrag[4];
#pragma unroll
            for (int nt = 0; nt < 4; ++nt)
                bfrag[nt] = *(const short8*)
                    &colF[(((ks * 4 + quad) * 64) + nt * 16 + cl) * 8];
#pragma unroll
            for (int mt = 0; mt < 4; ++mt)
#pragma unroll
                for (int nt = 0; nt < 4; ++nt)
                    acc[mt][nt] = __builtin_amdgcn_mfma_f32_16x16x32_bf16(
                        afrag[mt], bfrag[nt], acc[mt][nt], 0, 0, 0);
        }
    }

    const int quad = lane >> 4, cl = lane & 15;
#pragma unroll
    for (int mt = 0; mt < 4; ++mt) {
        int cobase = (wave * 4 + mt) * 16 + quad * 4;
#pragma unroll
        for (int r = 0; r < 4; ++r) {
            int co = cobase + r;
            float b = bias[co];
            float* op = out + (((size_t)n * COUT + co) * XH + ho) * XW;
#pragma unroll
            for (int nt = 0; nt < 4; ++nt)
                op[nt * 16 + cl] = acc[mt][nt][r] + b;
        }
    }
}

// Fallback 2: naive (ws < 1.18MB).
__global__ void dcn_naive(const float* __restrict__ x,
                          const float* __restrict__ off,
                          const float* __restrict__ msk,
                          const float* __restrict__ w,
                          const float* __restrict__ bias,
                          float* __restrict__ out) {
    int idx = blockIdx.x * 256 + threadIdx.x;
    if (idx >= 8 * COUT * XH * XW) return;
    int wo = idx & 63, ho = (idx >> 6) & 63, co = (idx >> 12) & 255, n = idx >> 20;
    float acc = bias[co];
    for (int k = 0; k < NK; ++k) {
        int obase = ((n * 18 + 2 * k) * XH + ho) * XW + wo;
        float dy = off[obase];
        float dx = off[obase + XH * XW];
        float mm = msk[((n * NK + k) * XH + ho) * XW + wo];
        float y  = (float)(ho - 1 + k / 3) + dy;
        float xs = (float)(wo - 1 + k % 3) + dx;
        float y0f = floorf(y), x0f = floorf(xs);
        float fy = y - y0f, fx = xs - x0f;
        int y0 = (int)y0f, x0 = (int)x0f;
        float vy0 = (y0 >= 0  && y0 < XH)     ? 1.f : 0.f;
        float vy1 = (y0 >= -1 && y0 < XH - 1) ? 1.f : 0.f;
        float vx0 = (x0 >= 0  && x0 < XW)     ? 1.f : 0.f;
        float vx1 = (x0 >= -1 && x0 < XW - 1) ? 1.f : 0.f;
        float w00 = (1.f - fy) * (1.f - fx) * mm * vy0 * vx0;
        float w01 = (1.f - fy) * fx         * mm * vy0 * vx1;
        float w10 = fy         * (1.f - fx) * mm * vy1 * vx0;
        float w11 = fy         * fx         * mm * vy1 * vx1;
        int y0c = min(max(y0, 0), XH - 1), y1c = min(max(y0 + 1, 0), XH - 1);
        int x0c = min(max(x0, 0), XW - 1), x1c = min(max(x0 + 1, 0), XW - 1);
        int o00 = y0c * XW + x0c, o01 = y0c * XW + x1c;
        int o10 = y1c * XW + x0c, o11 = y1c * XW + x1c;
        for (int c = 0; c < CIN; ++c) {
            const float* xp = x + ((size_t)(n * CIN + c)) * (XH * XW);
            float v = w00 * xp[o00] + w01 * xp[o01] + w10 * xp[o10] + w11 * xp[o11];
            acc += v * w[(co * CIN + c) * NK + k];
        }
    }
    out[idx] = acc;
}

// ---------------------------------------------------------------------------
extern "C" void kernel_launch(void* const* d_in, const int* in_sizes, int n_in,
                              void* d_out, int out_size, void* d_ws, size_t ws_size,
                              hipStream_t stream) {
    const float* x    = (const float*)d_in[0];
    const float* off  = (const float*)d_in[1];
    const float* msk  = (const float*)d_in[2];
    const float* w    = (const float*)d_in[3];
    const float* bias = (const float*)d_in[4];
    float* out = (float*)d_out;

    const size_t W3_BYTES = (size_t)9 * 16 * 8 * 64 * 8 * sizeof(short); // 1179648
    const size_t XT_BYTES = (size_t)8 * XH * XW * CIN * sizeof(short);   // 16777216

    if (ws_size >= W3_BYTES + XT_BYTES) {
        short* w3 = (short*)d_ws;
        short* xT = (short*)((char*)d_ws + W3_BYTES);
        dcn_prep<<<512 + 288, 256, 0, stream>>>(x, w, xT, w3);
        dcn_fused11<<<8 * 64, 512, 0, stream>>>(xT, off, msk, w3, bias, out);
    } else if (ws_size >= W3_BYTES) {
        short* w3 = (short*)d_ws;
        dcn_wprep_v1<<<(8 * 9 * 16 * 64 * 8 + 255) / 256, 256, 0, stream>>>(w, w3);
        dcn_fused_v1<<<8 * 64, 256, 0, stream>>>(x, off, msk, w3, bias, out);
    } else {
        dcn_naive<<<(8 * COUT * XH * XW + 255) / 256, 256, 0, stream>>>(
            x, off, msk, w, bias, out);
    }
}

// Round 10
// 149.053 us; speedup vs baseline: 1.0805x; 1.0143x over previous
//
#include <hip/hip_runtime.h>
#include <hip/hip_bf16.h>
#include <stdint.h>

// DCNv2 forward, fixed shapes: N=8, Cin=Cout=256, H=W=Ho=Wo=64, K=3x3, DG=1,
// stride=1, pad=1, dil=1.
//
// R12: R8 (the 63.0us best) + two-taps-per-phase. Barriers 17 -> 9, phase A
// has 4 gather items in flight (deeper MLP), phase B is 16 consecutive
// K-steps (longer prefetch runway). Everything else byte-identical to R8.
// Session ledger (mechanisms, do NOT retry):
//   R4/R7: reg-staged gathers across MFMA -> scratch spill at unified 128-reg
//          cap. NO register state may cross the MFMA cluster.
//   R5:    same-wave dbuf, 1 barrier/tap -> barrier re-aligns waves, no overlap.
//   R6:    producer/consumer waves -> static regalloc, producers carry dead
//          acc AGPRs -> spill.
//   R9:    4 small barrier domains/CU -> blocks phase-lock anyway.
//   R10:   A-red 2 -> +590MB L2 = +17us. A-red ~17us/unit, B-red ~1.4us/unit;
//          R8's A-red=1 x B-red=8 is the optimal corner.
//   R11:   32x32x16 -> only 2 acc chains/wave, MFMA latency-bound (-6us).
//          16x16x32 with 8 chains is the right shape here.

#define XH 64
#define XW 64
#define CIN 256
#define COUT 256
#define NK 9

typedef __attribute__((ext_vector_type(8))) short short8;   // 8 bf16 (4 VGPRs)
typedef __attribute__((ext_vector_type(4))) float floatx4;
typedef __attribute__((ext_vector_type(2))) float floatx2;
typedef __attribute__((ext_vector_type(4))) int   intx4;

__device__ __forceinline__ short f32_to_bf16_rne(float f) {
    union { float f; uint32_t u; } v; v.f = f;
    uint32_t u = v.u;
    uint32_t r = (u + 0x7FFFu + ((u >> 16) & 1u)) >> 16;
    return (short)(uint16_t)r;
}
__device__ __forceinline__ floatx2 bf16x2_to_f32x2(uint32_t u) {
    union { uint32_t u; float f; } lo, hi;
    lo.u = u << 16;
    hi.u = u & 0xFFFF0000u;
    floatx2 r; r.x = lo.f; r.y = hi.f;
    return r;
}

union U8 { short8 s; uint32_t u[4]; };

// ---------------------------------------------------------------------------
// Combined prep (identical to R8).
// Blocks [0,512): x (N,C,H,W) f32 -> xT (N,H,W,C) bf16, XCD-swizzled so the
//   XCD that writes rows [8x,8x+8) is the one that reads them in dcn_fused12.
// Blocks [512,800): weight swizzle -> w3 (bf16), 16x16x32 A-frag layout:
//   w3[(((k*8+ks)*16+mt)*64+lane)*8+j] = W[mt*16+(lane&15)][ks*32+(lane>>4)*8+j][k]
__global__ void dcn_prep(const float* __restrict__ x, const float* __restrict__ w,
                         short* __restrict__ xT, short* __restrict__ w3) {
    int b = blockIdx.x;
    int tid = threadIdx.x;
    if (b < 512) {
        int xcd = b & 7, slot = b >> 3;
        int h = xcd * 8 + (slot & 7);
        int n = slot >> 3;
        int q = tid & 15;        // w-quad
        int cgh = tid >> 4;      // 0..15
        short8* ob = (short8*)(xT + ((size_t)(n * XH + h)) * (XW * CIN));
        for (int it = 0; it < 2; ++it) {
            int cg = cgh + it * 16;          // channel granule 0..31
            const float* xb = x + ((size_t)(n * CIN + cg * 8)) * (XH * XW)
                                + h * XW + q * 4;
            floatx4 r[8];
#pragma unroll
            for (int j = 0; j < 8; ++j)
                r[j] = *(const floatx4*)(xb + (size_t)j * (XH * XW));
#pragma unroll
            for (int jw = 0; jw < 4; ++jw) {
                short8 pk;
#pragma unroll
                for (int j = 0; j < 8; ++j) pk[j] = f32_to_bf16_rne(r[j][jw]);
                ob[(q * 4 + jw) * 32 + cg] = pk;
            }
        }
    } else {
        int gidx = (b - 512) * 256 + tid;    // granule index, < 73728
        int lane = gidx & 63;
        int mt   = (gidx >> 6) & 15;
        int t    = gidx >> 10;               // k*8 + ks
        int ks   = t & 7;
        int k    = t >> 3;
        int co = mt * 16 + (lane & 15);
        int c0 = ks * 32 + (lane >> 4) * 8;
        short8 pk;
#pragma unroll
        for (int j = 0; j < 8; ++j)
            pk[j] = f32_to_bf16_rne(w[(co * CIN + c0 + j) * NK + k]);
        *(short8*)&w3[(size_t)gidx * 8] = pk;
    }
}

// ---------------------------------------------------------------------------
// Fused kernel. grid = N*Ho = 512, 512 threads (8 waves), XCD-swizzled.
// Two taps per phase pair: A(2k,2k+1 -> colF halves) | bar | B(16 K-steps)
// | bar. 9 barriers total (was 17). Tap 8 processed alone.
__launch_bounds__(512, 4)
__global__ void dcn_fused12(const short* __restrict__ xT,
                            const float* __restrict__ off,
                            const float* __restrict__ msk,
                            const short* __restrict__ w3,
                            const float* __restrict__ bias,
                            float* __restrict__ out) {
    // colF: 2 halves x 2048 granules of 16B. Within a half:
    // granule(chg,pos) at g = chg*64 + (pos^(chg&7))  (R8 swizzle, 0 conflicts)
    __shared__ short   colF[4096 * 8];       // 65536 B
    __shared__ floatx4 pairW[576];           //  9216 B
    __shared__ ushort4 pairO[576];           //  4608 B (raw spatial offs)

    const int bid = blockIdx.x;
    const int xcd = bid & 7, slot = bid >> 3;
    const int ho = xcd * 8 + (slot & 7);     // XCD x owns ho band [8x, 8x+8)
    const int n  = slot >> 3;
    const int tid  = threadIdx.x;
    const int wave = tid >> 6;
    const int lane = tid & 63;
    const int quad = lane >> 4, cl = lane & 15;

    // ---- bilinear params for 576 (wo, tap) pairs (mask folded into weights).
    for (int p = tid; p < 576; p += 512) {
        int wo = p & 63, k = p >> 6;
        int obase = ((n * 18 + 2 * k) * XH + ho) * XW + wo;
        float dy = off[obase];
        float dx = off[obase + XH * XW];
        float mm = msk[((n * NK + k) * XH + ho) * XW + wo];
        float y  = (float)(ho - 1 + k / 3) + dy;
        float xs = (float)(wo - 1 + k % 3) + dx;
        float y0f = floorf(y), x0f = floorf(xs);
        float fy = y - y0f, fx = xs - x0f;
        int y0 = (int)y0f, x0 = (int)x0f;
        float vy0 = (y0 >= 0  && y0 < XH)     ? 1.f : 0.f;
        float vy1 = (y0 >= -1 && y0 < XH - 1) ? 1.f : 0.f;
        float vx0 = (x0 >= 0  && x0 < XW)     ? 1.f : 0.f;
        float vx1 = (x0 >= -1 && x0 < XW - 1) ? 1.f : 0.f;
        floatx4 wv;
        wv.x = (1.f - fy) * (1.f - fx) * mm * vy0 * vx0;
        wv.y = (1.f - fy) * fx         * mm * vy0 * vx1;
        wv.z = fy         * (1.f - fx) * mm * vy1 * vx0;
        wv.w = fy         * fx         * mm * vy1 * vx1;
        int y0c = min(max(y0, 0), XH - 1), y1c = min(max(y0 + 1, 0), XH - 1);
        int x0c = min(max(x0, 0), XW - 1), x1c = min(max(x0 + 1, 0), XW - 1);
        ushort4 ov;
        ov.x = (unsigned short)(y0c * XW + x0c);
        ov.y = (unsigned short)(y0c * XW + x1c);
        ov.z = (unsigned short)(y1c * XW + x0c);
        ov.w = (unsigned short)(y1c * XW + x1c);
        pairW[p] = wv;
        pairO[p] = ov;
    }
    __syncthreads();

    floatx4 acc[2][4];
#pragma unroll
    for (int mt = 0; mt < 2; ++mt)
#pragma unroll
        for (int nt = 0; nt < 4; ++nt)
            acc[mt][nt] = (floatx4)(0.f);

    const short8* xTv = (const short8*)(xT + (size_t)n * (XH * XW * CIN));
    const short8* w3v = (const short8*)w3;

    // ---- phase-B address hoists: swizzle has only 2 per-ks variants -------
    int boffE[4], boffO[4];
#pragma unroll
    for (int nt = 0; nt < 4; ++nt) {
        boffE[nt] = (nt * 16 + cl) ^ quad;         // ks even: sw = quad
        boffO[nt] = ((nt * 16 + cl) ^ quad) ^ 4;   // ks odd:  sw = quad^4
    }
    const short8* cbase = (const short8*)colF;

    // ---- phase A: paired gathers (chg, chg+16) into half h of colF.
    // Identical memory pattern to R8 (0 conflicts, 256B+256B runs).
    auto sampleTap = [&](int k, int half) {
        short* dst = colF + half * (2048 * 8);
        for (int it = 0; it < 2; ++it) {
            int pidx = it * 512 + tid;
            int cp  = pidx & 15;
            int pos = pidx >> 4;
            int p = k * 64 + pos;
            ushort4 ov = pairO[p];
            const short8* q00 = xTv + ((int)ov.x * 32 + cp);
            const short8* q01 = xTv + ((int)ov.y * 32 + cp);
            const short8* q10 = xTv + ((int)ov.z * 32 + cp);
            const short8* q11 = xTv + ((int)ov.w * 32 + cp);
            U8 a0, b0, c0, d0, a1, b1, c1, d1;
            a0.s = q00[0]; a1.s = q00[16];
            b0.s = q01[0]; b1.s = q01[16];
            c0.s = q10[0]; c1.s = q10[16];
            d0.s = q11[0]; d1.s = q11[16];
            floatx4 wv = pairW[p];
            U8 pk0, pk1;
#pragma unroll
            for (int i = 0; i < 4; ++i) {
                floatx2 v0 = bf16x2_to_f32x2(a0.u[i]) * wv.x
                           + bf16x2_to_f32x2(b0.u[i]) * wv.y
                           + bf16x2_to_f32x2(c0.u[i]) * wv.z
                           + bf16x2_to_f32x2(d0.u[i]) * wv.w;
                floatx2 v1 = bf16x2_to_f32x2(a1.u[i]) * wv.x
                           + bf16x2_to_f32x2(b1.u[i]) * wv.y
                           + bf16x2_to_f32x2(c1.u[i]) * wv.z
                           + bf16x2_to_f32x2(d1.u[i]) * wv.w;
                float2 f0; f0.x = v0.x; f0.y = v0.y;
                float2 f1; f1.x = v1.x; f1.y = v1.y;
                __hip_bfloat162 h0 = __float22bfloat162_rn(f0);
                __hip_bfloat162 h1 = __float22bfloat162_rn(f1);
                __builtin_memcpy(&pk0.u[i], &h0, 4);
                __builtin_memcpy(&pk1.u[i], &h1, 4);
            }
            int sw = pos ^ (cp & 7);
            *(short8*)&dst[(cp * 64 + sw) * 8] = pk0.s;
            *(short8*)&dst[((cp + 16) * 64 + sw) * 8] = pk1.s;
        }
    };

    // ---- phase B: 8 K-steps of tap k from half h (R8's loop) ----
    auto tapB = [&](int k, int half) {
        const short8* hb = cbase + half * 2048;
        const short8* ap = w3v + ((k * 8 * 16) + wave * 2) * 64 + lane;
#pragma unroll
        for (int ks = 0; ks < 8; ++ks) {
            short8 afrag0 = ap[0];
            short8 afrag1 = ap[64];
            const short8* cb = hb + (ks * 256 + quad * 64);
            short8 bfrag[4];
#pragma unroll
            for (int nt = 0; nt < 4; ++nt)
                bfrag[nt] = cb[(ks & 1) ? boffO[nt] : boffE[nt]];
#pragma unroll
            for (int nt = 0; nt < 4; ++nt)
                acc[0][nt] = __builtin_amdgcn_mfma_f32_16x16x32_bf16(
                    afrag0, bfrag[nt], acc[0][nt], 0, 0, 0);
#pragma unroll
            for (int nt = 0; nt < 4; ++nt)
                acc[1][nt] = __builtin_amdgcn_mfma_f32_16x16x32_bf16(
                    afrag1, bfrag[nt], acc[1][nt], 0, 0, 0);
            ap += 16 * 64;
        }
    };

    // ---- prologue: taps 0,1 ----
    sampleTap(0, 0);
    sampleTap(1, 1);

#pragma unroll 1
    for (int kp = 0; kp < 4; ++kp) {
        __syncthreads();                       // phase A of pair complete
        __builtin_amdgcn_s_setprio(1);
        tapB(2 * kp, 0);
        tapB(2 * kp + 1, 1);
        __builtin_amdgcn_s_setprio(0);
        __syncthreads();                       // phase B done reading colF
        if (kp < 3) {
            sampleTap(2 * kp + 2, 0);
            sampleTap(2 * kp + 3, 1);
        } else {
            sampleTap(8, 0);
        }
    }
    __syncthreads();
    __builtin_amdgcn_s_setprio(1);
    tapB(8, 0);
    __builtin_amdgcn_s_setprio(0);

    // ---- epilogue: D layout col=lane&15 (pos), row=(lane>>4)*4+reg (co) ----
#pragma unroll
    for (int mt = 0; mt < 2; ++mt) {
        int cobase = (wave * 2 + mt) * 16 + quad * 4;
#pragma unroll
        for (int r = 0; r < 4; ++r) {
            int co = cobase + r;
            float b = bias[co];
            float* op = out + (((size_t)n * COUT + co) * XH + ho) * XW;
#pragma unroll
            for (int nt = 0; nt < 4; ++nt)
                op[nt * 16 + cl] = acc[mt][nt][r] + b;
        }
    }
}

// ===========================================================================
// Fallback 1 (ws in [1.18MB, 18MB)): round-1 fused kernel (NCHW gathers).
__global__ void dcn_wprep_v1(const float* __restrict__ w, short* __restrict__ w3) {
    int idx = blockIdx.x * 256 + threadIdx.x;
    if (idx >= 8 * 9 * 16 * 64 * 8) return;
    int j    = idx & 7;
    int lane = (idx >> 3) & 63;
    int mt   = (idx >> 9) & 15;
    int t    = idx >> 13;
    int ks   = t % 9;
    int cc   = t / 9;
    int co = mt * 16 + (lane & 15);
    int c  = cc * 32 + (lane >> 4) * 8 + j;
    w3[idx] = f32_to_bf16_rne(w[(co * CIN + c) * NK + ks]);
}

__launch_bounds__(256, 2)
__global__ void dcn_fused_v1(const float* __restrict__ x,
                             const float* __restrict__ off,
                             const float* __restrict__ msk,
                             const short* __restrict__ w3,
                             const float* __restrict__ bias,
                             float* __restrict__ out) {
    __shared__ short  colF[2304 * 8];
    __shared__ floatx4 pairW[576];
    __shared__ intx4   pairO[576];

    const int bid = blockIdx.x;
    const int n  = bid >> 6;
    const int ho = bid & 63;
    const int tid  = threadIdx.x;
    const int wave = tid >> 6;
    const int lane = tid & 63;

    for (int p = tid; p < 576; p += 256) {
        int wo = p & 63, k = p >> 6;
        int obase = ((n * 18 + 2 * k) * XH + ho) * XW + wo;
        float dy = off[obase];
        float dx = off[obase + XH * XW];
        float mm = msk[((n * NK + k) * XH + ho) * XW + wo];
        float y  = (float)(ho - 1 + k / 3) + dy;
        float xs = (float)(wo - 1 + k % 3) + dx;
        float y0f = floorf(y), x0f = floorf(xs);
        float fy = y - y0f, fx = xs - x0f;
        int y0 = (int)y0f, x0 = (int)x0f;
        float vy0 = (y0 >= 0  && y0 < XH)     ? 1.f : 0.f;
        float vy1 = (y0 >= -1 && y0 < XH - 1) ? 1.f : 0.f;
        float vx0 = (x0 >= 0  && x0 < XW)     ? 1.f : 0.f;
        float vx1 = (x0 >= -1 && x0 < XW - 1) ? 1.f : 0.f;
        floatx4 wv;
        wv.x = (1.f - fy) * (1.f - fx) * mm * vy0 * vx0;
        wv.y = (1.f - fy) * fx         * mm * vy0 * vx1;
        wv.z = fy         * (1.f - fx) * mm * vy1 * vx0;
        wv.w = fy         * fx         * mm * vy1 * vx1;
        int y0c = min(max(y0, 0), XH - 1), y1c = min(max(y0 + 1, 0), XH - 1);
        int x0c = min(max(x0, 0), XW - 1), x1c = min(max(x0 + 1, 0), XW - 1);
        intx4 ov;
        ov.x = y0c * XW + x0c; ov.y = y0c * XW + x1c;
        ov.z = y1c * XW + x0c; ov.w = y1c * XW + x1c;
        pairW[p] = wv;
        pairO[p] = ov;
    }
    __syncthreads();

    floatx4 acc[4][4];
#pragma unroll
    for (int mt = 0; mt < 4; ++mt)
#pragma unroll
        for (int nt = 0; nt < 4; ++nt)
            acc[mt][nt] = (floatx4)(0.f);

    const float* xn = x + (size_t)n * CIN * (XH * XW);
    const short8* w3v = (const short8*)w3;

    for (int cc = 0; cc < 8; ++cc) {
        __syncthreads();
        for (int it = 0; it < 9; ++it) {
            int item = it * 256 + tid;
            int pos  = item & 63;
            int r    = item >> 6;
            int k    = r >> 2;
            int csub = r & 3;
            int p = k * 64 + pos;
            floatx4 wv = pairW[p];
            intx4   ov = pairO[p];
            const float* xc = xn + (size_t)(cc * 32 + csub * 8) * (XH * XW);
            short8 pk;
#pragma unroll
            for (int i = 0; i < 8; ++i) {
                const float* xp = xc + i * (XH * XW);
                float v = wv.x * xp[ov.x] + wv.y * xp[ov.y] +
                          wv.z * xp[ov.z] + wv.w * xp[ov.w];
                pk[i] = f32_to_bf16_rne(v);
            }
            *(short8*)&colF[(((k * 4 + csub) * 64) + pos) * 8] = pk;
        }
        __syncthreads();

        const int quad = lane >> 4, cl = lane & 15;
        for (int ks = 0; ks < 9; ++ks) {
            short8 afrag[4];
#pragma unroll
            for (int mt = 0; mt < 4; ++mt) {
                int mtg = wave * 4 + mt;
                afrag[mt] = w3v[(((cc * 9 + ks) * 16 + mtg) * 64) + lane];
            }
            short8 bfrag[4];
#pragma unroll
            for (int nt = 0; nt < 4; ++nt)
                bfrag[nt] = *(const short8*)
                    &colF[(((ks * 4 + quad) * 64) + nt * 16 + cl) * 8];
#pragma unroll
            for (int mt = 0; mt < 4; ++mt)
#pragma unroll
                for (int nt = 0; nt < 4; ++nt)
                    acc[mt][nt] = __builtin_amdgcn_mfma_f32_16x16x32_bf16(
                        afrag[mt], bfrag[nt], acc[mt][nt], 0, 0, 0);
        }
    }

    const int quad = lane >> 4, cl = lane & 15;
#pragma unroll
    for (int mt = 0; mt < 4; ++mt) {
        int cobase = (wave * 4 + mt) * 16 + quad * 4;
#pragma unroll
        for (int r = 0; r < 4; ++r) {
            int co = cobase + r;
            float b = bias[co];
            float* op = out + (((size_t)n * COUT + co) * XH + ho) * XW;
#pragma unroll
            for (int nt = 0; nt < 4; ++nt)
                op[nt * 16 + cl] = acc[mt][nt][r] + b;
        }
    }
}

// Fallback 2: naive (ws < 1.18MB).
__global__ void dcn_naive(const float* __restrict__ x,
                          const float* __restrict__ off,
                          const float* __restrict__ msk,
                          const float* __restrict__ w,
                          const float* __restrict__ bias,
                          float* __restrict__ out) {
    int idx = blockIdx.x * 256 + threadIdx.x;
    if (idx >= 8 * COUT * XH * XW) return;
    int wo = idx & 63, ho = (idx >> 6) & 63, co = (idx >> 12) & 255, n = idx >> 20;
    float acc = bias[co];
    for (int k = 0; k < NK; ++k) {
        int obase = ((n * 18 + 2 * k) * XH + ho) * XW + wo;
        float dy = off[obase];
        float dx = off[obase + XH * XW];
        float mm = msk[((n * NK + k) * XH + ho) * XW + wo];
        float y  = (float)(ho - 1 + k / 3) + dy;
        float xs = (float)(wo - 1 + k % 3) + dx;
        float y0f = floorf(y), x0f = floorf(xs);
        float fy = y - y0f, fx = xs - x0f;
        int y0 = (int)y0f, x0 = (int)x0f;
        float vy0 = (y0 >= 0  && y0 < XH)     ? 1.f : 0.f;
        float vy1 = (y0 >= -1 && y0 < XH - 1) ? 1.f : 0.f;
        float vx0 = (x0 >= 0  && x0 < XW)     ? 1.f : 0.f;
        float vx1 = (x0 >= -1 && x0 < XW - 1) ? 1.f : 0.f;
        float w00 = (1.f - fy) * (1.f - fx) * mm * vy0 * vx0;
        float w01 = (1.f - fy) * fx         * mm * vy0 * vx1;
        float w10 = fy         * (1.f - fx) * mm * vy1 * vx0;
        float w11 = fy         * fx         * mm * vy1 * vx1;
        int y0c = min(max(y0, 0), XH - 1), y1c = min(max(y0 + 1, 0), XH - 1);
        int x0c = min(max(x0, 0), XW - 1), x1c = min(max(x0 + 1, 0), XW - 1);
        int o00 = y0c * XW + x0c, o01 = y0c * XW + x1c;
        int o10 = y1c * XW + x0c, o11 = y1c * XW + x1c;
        for (int c = 0; c < CIN; ++c) {
            const float* xp = x + ((size_t)(n * CIN + c)) * (XH * XW);
            float v = w00 * xp[o00] + w01 * xp[o01] + w10 * xp[o10] + w11 * xp[o11];
            acc += v * w[(co * CIN + c) * NK + k];
        }
    }
    out[idx] = acc;
}

// ---------------------------------------------------------------------------
extern "C" void kernel_launch(void* const* d_in, const int* in_sizes, int n_in,
                              void* d_out, int out_size, void* d_ws, size_t ws_size,
                              hipStream_t stream) {
    const float* x    = (const float*)d_in[0];
    const float* off  = (const float*)d_in[1];
    const float* msk  = (const float*)d_in[2];
    const float* w    = (const float*)d_in[3];
    const float* bias = (const float*)d_in[4];
    float* out = (float*)d_out;

    const size_t W3_BYTES = (size_t)9 * 8 * 16 * 64 * 8 * sizeof(short); // 1179648
    const size_t XT_BYTES = (size_t)8 * XH * XW * CIN * sizeof(short);   // 16777216

    if (ws_size >= W3_BYTES + XT_BYTES) {
        short* w3 = (short*)d_ws;
        short* xT = (short*)((char*)d_ws + W3_BYTES);
        dcn_prep<<<512 + 288, 256, 0, stream>>>(x, w, xT, w3);
        dcn_fused12<<<8 * 64, 512, 0, stream>>>(xT, off, msk, w3, bias, out);
    } else if (ws_size >= W3_BYTES) {
        short* w3 = (short*)d_ws;
        dcn_wprep_v1<<<(8 * 9 * 16 * 64 * 8 + 255) / 256, 256, 0, stream>>>(w, w3);
        dcn_fused_v1<<<8 * 64, 256, 0, stream>>>(x, off, msk, w3, bias, out);
    } else {
        dcn_naive<<<(8 * COUT * XH * XW + 255) / 256, 256, 0, stream>>>(
            x, off, msk, w, bias, out);
    }
}